// Round 1
// baseline (73.052 us; speedup 1.0000x reference)
//
#include <hip/hip_runtime.h>
#include <hip/hip_bf16.h>

typedef __bf16 bf16;
typedef __attribute__((ext_vector_type(8))) __bf16 bf16x8;
typedef __attribute__((ext_vector_type(4))) float f32x4;

#define BIG_NEG 1000000000000.0f
// ln(1000)/32
#define NEG_LOG_STEP 0.21586735253866545f

static __device__ inline uint2 pack4_bf16(float4 v) {
    union { bf16 h[4]; uint2 u; } t;
    t.h[0] = (bf16)v.x; t.h[1] = (bf16)v.y; t.h[2] = (bf16)v.z; t.h[3] = (bf16)v.w;
    return t.u;
}

// Stage 1: C[m,n] = X[m,:]·W[n,:] + b[n]  (M=4096=B*S, N=2048=L*128, K=768)
// then RoPE on q (d<64) / k (d>=64) halves, pack bf16 into q_ws/k_ws [b][l][s][d].
__global__ __launch_bounds__(256) void proj_rope_kernel(
    const float* __restrict__ X, const float* __restrict__ W,
    const float* __restrict__ bias,
    bf16* __restrict__ q_ws, bf16* __restrict__ k_ws)
{
    const int K = 768;
    __shared__ __align__(16) bf16 As[128][40];  // 128 rows (m) x 32 k, pad to 40
    __shared__ __align__(16) bf16 Bs[128][40];  // 128 rows (n) x 32 k

    const int tid  = threadIdx.x;
    const int lane = tid & 63;
    const int wave = tid >> 6;          // 0..3
    const int wr   = wave >> 1;         // wave row (2x2)
    const int wc   = wave & 1;
    const int brow = blockIdx.x * 128;  // m block
    const int bcol = blockIdx.y * 128;  // n block
    const int lane15 = lane & 15;
    const int kq = (lane >> 4) * 8;     // k offset of this lane's fragment

    f32x4 acc[4][4] = {};

    for (int k0 = 0; k0 < K; k0 += 32) {
        // stage A (X) and B (W) 128x32 tiles, f32 -> bf16
        #pragma unroll
        for (int pass = 0; pass < 4; ++pass) {
            int e   = (pass * 256 + tid) * 4;   // element in 128x32
            int row = e >> 5;
            int col = e & 31;
            float4 xa = *reinterpret_cast<const float4*>(&X[(size_t)(brow + row) * K + k0 + col]);
            *reinterpret_cast<uint2*>(&As[row][col]) = pack4_bf16(xa);
            float4 wa = *reinterpret_cast<const float4*>(&W[(size_t)(bcol + row) * K + k0 + col]);
            *reinterpret_cast<uint2*>(&Bs[row][col]) = pack4_bf16(wa);
        }
        __syncthreads();

        bf16x8 af[4], bfv[4];
        #pragma unroll
        for (int mf = 0; mf < 4; ++mf)
            af[mf] = *reinterpret_cast<bf16x8*>(&As[wr * 64 + mf * 16 + lane15][kq]);
        #pragma unroll
        for (int nf = 0; nf < 4; ++nf)
            bfv[nf] = *reinterpret_cast<bf16x8*>(&Bs[wc * 64 + nf * 16 + lane15][kq]);
        #pragma unroll
        for (int mf = 0; mf < 4; ++mf)
            #pragma unroll
            for (int nf = 0; nf < 4; ++nf)
                acc[mf][nf] = __builtin_amdgcn_mfma_f32_16x16x32_bf16(
                    af[mf], bfv[nf], acc[mf][nf], 0, 0, 0);
        __syncthreads();
    }

    // Epilogue: bias + RoPE + pack to ws.
    // C/D layout: col = lane&15, row = (lane>>4)*4 + r  [m89]
    const int rowbase = brow + wr * 64 + (lane >> 4) * 4;
    const int colbase = bcol + wc * 64;
    #pragma unroll
    for (int nf = 0; nf < 4; ++nf) {
        int n = colbase + nf * 16 + lane15;
        int d = n & 127;            // channel within label block
        int l = n >> 7;             // label
        int p = (d & 63) >> 1;      // rotary pair index
        float theta = __expf(-(float)p * NEG_LOG_STEP);
        float bn = bias[n];
        bool odd = (d & 1) != 0;
        bf16* dst = (d < 64) ? q_ws : k_ws;   // uniform per wave (16-col span)
        int dd = d & 63;
        #pragma unroll
        for (int mf = 0; mf < 4; ++mf) {
            f32x4 v4 = acc[mf][nf];
            #pragma unroll
            for (int r = 0; r < 4; ++r) {
                int m = rowbase + mf * 16 + r;
                float v  = v4[r] + bn;
                float pv = __shfl_xor(v, 1);  // partner column (d ^ 1), same row
                int s = m & 511;
                int b = m >> 9;
                float ang = (float)s * theta;
                float sn, cs;
                __sincosf(ang, &sn, &cs);
                float o = odd ? (v * cs + pv * sn) : (v * cs - pv * sn);
                dst[(((size_t)(b * 16 + l) * 512) + s) * 64 + dd] = (bf16)o;
            }
        }
    }
}

// Stage 2: per (b,l): logits[m,n] = sum_d q[m,d]*k[n,d]; mask + tril + scale.
__global__ __launch_bounds__(256) void attn_kernel(
    const bf16* __restrict__ q_ws, const bf16* __restrict__ k_ws,
    const int* __restrict__ mask, float* __restrict__ out)
{
    __shared__ __align__(16) bf16 Qs[128][72];  // 128 rows (m) x 64 k, pad to 72
    __shared__ __align__(16) bf16 Ks[128][72];  // 128 rows (n) x 64 k

    const int tid  = threadIdx.x;
    const int lane = tid & 63;
    const int wave = tid >> 6;
    const int wr   = wave >> 1;
    const int wc   = wave & 1;
    const int bl   = blockIdx.z;        // b*16 + l
    const int brow = blockIdx.x * 128;  // m
    const int bcol = blockIdx.y * 128;  // n
    const int lane15 = lane & 15;

    const bf16* qbase = q_ws + (size_t)bl * 512 * 64;
    const bf16* kbase = k_ws + (size_t)bl * 512 * 64;

    #pragma unroll
    for (int pass = 0; pass < 4; ++pass) {
        int e   = (pass * 256 + tid) * 8;  // element in 128x64
        int row = e >> 6;
        int col = e & 63;
        *reinterpret_cast<uint4*>(&Qs[row][col]) =
            *reinterpret_cast<const uint4*>(&qbase[(size_t)(brow + row) * 64 + col]);
        *reinterpret_cast<uint4*>(&Ks[row][col]) =
            *reinterpret_cast<const uint4*>(&kbase[(size_t)(bcol + row) * 64 + col]);
    }
    __syncthreads();

    f32x4 acc[4][4] = {};
    #pragma unroll
    for (int ks = 0; ks < 2; ++ks) {
        int kq = ks * 32 + (lane >> 4) * 8;
        bf16x8 af[4], bfv[4];
        #pragma unroll
        for (int mf = 0; mf < 4; ++mf)
            af[mf] = *reinterpret_cast<bf16x8*>(&Qs[wr * 64 + mf * 16 + lane15][kq]);
        #pragma unroll
        for (int nf = 0; nf < 4; ++nf)
            bfv[nf] = *reinterpret_cast<bf16x8*>(&Ks[wc * 64 + nf * 16 + lane15][kq]);
        #pragma unroll
        for (int mf = 0; mf < 4; ++mf)
            #pragma unroll
            for (int nf = 0; nf < 4; ++nf)
                acc[mf][nf] = __builtin_amdgcn_mfma_f32_16x16x32_bf16(
                    af[mf], bfv[nf], acc[mf][nf], 0, 0, 0);
    }

    const int b = bl >> 4;
    const int* mrow = mask + b * 512;
    const int rowbase = brow + wr * 64 + (lane >> 4) * 4;
    const int colbase = bcol + wc * 64;
    #pragma unroll
    for (int nf = 0; nf < 4; ++nf) {
        int n = colbase + nf * 16 + lane15;
        float pf = (float)mrow[n];
        float mterm = (1.0f - pf) * BIG_NEG;
        #pragma unroll
        for (int mf = 0; mf < 4; ++mf) {
            f32x4 v4 = acc[mf][nf];
            #pragma unroll
            for (int r = 0; r < 4; ++r) {
                int m = rowbase + mf * 16 + r;
                float v = v4[r] * pf - mterm - ((m > n) ? BIG_NEG : 0.0f);
                out[((size_t)bl * 512 + m) * 512 + n] = v * 0.125f;
            }
        }
    }
}

extern "C" void kernel_launch(void* const* d_in, const int* in_sizes, int n_in,
                              void* d_out, int out_size, void* d_ws, size_t ws_size,
                              hipStream_t stream) {
    const float* X    = (const float*)d_in[0];   // (8,512,768)
    const int*   mask = (const int*)d_in[1];     // (8,512)
    const float* W    = (const float*)d_in[2];   // (2048,768)
    const float* bias = (const float*)d_in[3];   // (2048,)

    float* out = (float*)d_out;                  // (8,16,512,512)
    bf16* q_ws = (bf16*)d_ws;                    // [8][16][512][64]
    bf16* k_ws = q_ws + (size_t)8 * 16 * 512 * 64;

    proj_rope_kernel<<<dim3(32, 16), 256, 0, stream>>>(X, W, bias, q_ws, k_ws);
    attn_kernel<<<dim3(4, 4, 128), 256, 0, stream>>>(q_ws, k_ws, mask, out);
}

// Round 2
// 67.198 us; speedup vs baseline: 1.0871x; 1.0871x over previous
//
#include <hip/hip_runtime.h>
#include <hip/hip_bf16.h>

typedef __bf16 bf16;
typedef __attribute__((ext_vector_type(8))) __bf16 bf16x8;
typedef __attribute__((ext_vector_type(4))) float f32x4;

#define BIG_NEG 1000000000000.0f
// ln(1000)/32
#define NEG_LOG_STEP 0.21586735253866545f

#define GLOAD_LDS16(g, l)                                                     \
    __builtin_amdgcn_global_load_lds(                                         \
        (const __attribute__((address_space(1))) void*)(g),                   \
        (__attribute__((address_space(3))) void*)(l), 16, 0, 0)

static __device__ inline uint2 pack4_bf16(float4 v) {
    union { bf16 h[4]; uint2 u; } t;
    t.h[0] = (bf16)v.x; t.h[1] = (bf16)v.y; t.h[2] = (bf16)v.z; t.h[3] = (bf16)v.w;
    return t.u;
}

// Kernel 0: convert X (8*512*768 f32) and W (2048*768 f32) to bf16.
__global__ __launch_bounds__(256) void convert_kernel(
    const float* __restrict__ X, const float* __restrict__ W,
    bf16* __restrict__ Xb, bf16* __restrict__ Wb)
{
    const int NX8 = (8 * 512 * 768) / 8;   // 1,572,864 groups of 8
    int idx = blockIdx.x * 256 + threadIdx.x;
    const float* src; bf16* dst; int i;
    if (idx < NX8) { src = X; dst = Xb; i = idx; }
    else           { src = W; dst = Wb; i = idx - NX8; }
    float4 a = reinterpret_cast<const float4*>(src)[i * 2];
    float4 b = reinterpret_cast<const float4*>(src)[i * 2 + 1];
    uint2 lo = pack4_bf16(a), hi = pack4_bf16(b);
    uint4 o; o.x = lo.x; o.y = lo.y; o.z = hi.x; o.w = hi.y;
    reinterpret_cast<uint4*>(dst)[i] = o;
}

// Stage 1: C[m,n] = X[m,:]·W[n,:] + b[n]  (M=4096, N=2048, K=768), bf16 MFMA,
// global_load_lds staging; RoPE epilogue packs bf16 q/k into ws [b][l][s][d].
__global__ __launch_bounds__(256) void proj_rope_kernel(
    const bf16* __restrict__ A, const bf16* __restrict__ B,
    const float* __restrict__ bias,
    bf16* __restrict__ q_ws, bf16* __restrict__ k_ws)
{
    const int K = 768;
    __shared__ __align__(16) bf16 As[128][32];   // linear — required by global_load_lds
    __shared__ __align__(16) bf16 Bs[128][32];

    const int tid  = threadIdx.x;
    const int lane = tid & 63;
    const int wave = tid >> 6;          // 0..3
    const int wr   = wave >> 1;
    const int wc   = wave & 1;
    const int brow = blockIdx.x * 128;  // m block
    const int bcol = blockIdx.y * 128;  // n block
    const int lane15 = lane & 15;
    const int kq = (lane >> 4) * 8;
    const int srow = lane >> 2;         // staging: row within 16-row wave chunk
    const int scol = (lane & 3) * 8;    // staging: col (8 bf16 = 16B per lane)

    f32x4 acc[4][4] = {};

    for (int k0 = 0; k0 < K; k0 += 32) {
        #pragma unroll
        for (int p = 0; p < 2; ++p) {
            int r0 = p * 64 + wave * 16;
            GLOAD_LDS16(A + (size_t)(brow + r0 + srow) * K + k0 + scol, &As[r0][0]);
            GLOAD_LDS16(B + (size_t)(bcol + r0 + srow) * K + k0 + scol, &Bs[r0][0]);
        }
        __syncthreads();

        bf16x8 af[4], bfv[4];
        #pragma unroll
        for (int mf = 0; mf < 4; ++mf)
            af[mf] = *reinterpret_cast<bf16x8*>(&As[wr * 64 + mf * 16 + lane15][kq]);
        #pragma unroll
        for (int nf = 0; nf < 4; ++nf)
            bfv[nf] = *reinterpret_cast<bf16x8*>(&Bs[wc * 64 + nf * 16 + lane15][kq]);
        #pragma unroll
        for (int mf = 0; mf < 4; ++mf)
            #pragma unroll
            for (int nf = 0; nf < 4; ++nf)
                acc[mf][nf] = __builtin_amdgcn_mfma_f32_16x16x32_bf16(
                    af[mf], bfv[nf], acc[mf][nf], 0, 0, 0);
        __syncthreads();
    }

    // Epilogue: bias + RoPE + pack to ws.  C/D layout: col=lane&15, row=(lane>>4)*4+r
    const int rowbase = brow + wr * 64 + (lane >> 4) * 4;
    const int colbase = bcol + wc * 64;
    #pragma unroll
    for (int nf = 0; nf < 4; ++nf) {
        int n = colbase + nf * 16 + lane15;
        int d = n & 127;            // channel within label block
        int l = n >> 7;             // label
        int p = (d & 63) >> 1;      // rotary pair index
        float theta = __expf(-(float)p * NEG_LOG_STEP);
        float bn = bias[n];
        bool odd = (d & 1) != 0;
        bf16* dst = (d < 64) ? q_ws : k_ws;   // uniform per wave (16-col span)
        int dd = d & 63;
        #pragma unroll
        for (int mf = 0; mf < 4; ++mf) {
            f32x4 v4 = acc[mf][nf];
            #pragma unroll
            for (int r = 0; r < 4; ++r) {
                int m = rowbase + mf * 16 + r;
                float v  = v4[r] + bn;
                float pv = __shfl_xor(v, 1);  // partner column (d ^ 1), same row
                int s = m & 511;
                int b = m >> 9;
                float ang = (float)s * theta;
                float sn, cs;
                __sincosf(ang, &sn, &cs);
                float o = odd ? (v * cs + pv * sn) : (v * cs - pv * sn);
                dst[(((size_t)(b * 16 + l) * 512) + s) * 64 + dd] = (bf16)o;
            }
        }
    }
}

// Stage 2: per (b,l): logits[m,n] = sum_d q[m,d]*k[n,d]; mask + tril + scale.
__global__ __launch_bounds__(256) void attn_kernel(
    const bf16* __restrict__ q_ws, const bf16* __restrict__ k_ws,
    const int* __restrict__ mask, float* __restrict__ out)
{
    __shared__ __align__(16) bf16 Qs[128][72];
    __shared__ __align__(16) bf16 Ks[128][72];

    const int tid  = threadIdx.x;
    const int lane = tid & 63;
    const int wave = tid >> 6;
    const int wr   = wave >> 1;
    const int wc   = wave & 1;
    const int bl   = blockIdx.z;        // b*16 + l
    const int brow = blockIdx.x * 128;  // m
    const int bcol = blockIdx.y * 128;  // n
    const int lane15 = lane & 15;

    const bf16* qbase = q_ws + (size_t)bl * 512 * 64;
    const bf16* kbase = k_ws + (size_t)bl * 512 * 64;

    #pragma unroll
    for (int pass = 0; pass < 4; ++pass) {
        int e   = (pass * 256 + tid) * 8;  // element in 128x64
        int row = e >> 6;
        int col = e & 63;
        *reinterpret_cast<uint4*>(&Qs[row][col]) =
            *reinterpret_cast<const uint4*>(&qbase[(size_t)(brow + row) * 64 + col]);
        *reinterpret_cast<uint4*>(&Ks[row][col]) =
            *reinterpret_cast<const uint4*>(&kbase[(size_t)(bcol + row) * 64 + col]);
    }
    __syncthreads();

    f32x4 acc[4][4] = {};
    #pragma unroll
    for (int ks = 0; ks < 2; ++ks) {
        int kq = ks * 32 + (lane >> 4) * 8;
        bf16x8 af[4], bfv[4];
        #pragma unroll
        for (int mf = 0; mf < 4; ++mf)
            af[mf] = *reinterpret_cast<bf16x8*>(&Qs[wr * 64 + mf * 16 + lane15][kq]);
        #pragma unroll
        for (int nf = 0; nf < 4; ++nf)
            bfv[nf] = *reinterpret_cast<bf16x8*>(&Ks[wc * 64 + nf * 16 + lane15][kq]);
        #pragma unroll
        for (int mf = 0; mf < 4; ++mf)
            #pragma unroll
            for (int nf = 0; nf < 4; ++nf)
                acc[mf][nf] = __builtin_amdgcn_mfma_f32_16x16x32_bf16(
                    af[mf], bfv[nf], acc[mf][nf], 0, 0, 0);
    }

    const int b = bl >> 4;
    const int* mrow = mask + b * 512;
    const int rowbase = brow + wr * 64 + (lane >> 4) * 4;
    const int colbase = bcol + wc * 64;
    #pragma unroll
    for (int nf = 0; nf < 4; ++nf) {
        int n = colbase + nf * 16 + lane15;
        float pf = (float)mrow[n];
        float mterm = (1.0f - pf) * BIG_NEG;
        #pragma unroll
        for (int mf = 0; mf < 4; ++mf) {
            f32x4 v4 = acc[mf][nf];
            #pragma unroll
            for (int r = 0; r < 4; ++r) {
                int m = rowbase + mf * 16 + r;
                float v = v4[r] * pf - mterm - ((m > n) ? BIG_NEG : 0.0f);
                out[((size_t)bl * 512 + m) * 512 + n] = v * 0.125f;
            }
        }
    }
}

extern "C" void kernel_launch(void* const* d_in, const int* in_sizes, int n_in,
                              void* d_out, int out_size, void* d_ws, size_t ws_size,
                              hipStream_t stream) {
    const float* X    = (const float*)d_in[0];   // (8,512,768)
    const int*   mask = (const int*)d_in[1];     // (8,512)
    const float* W    = (const float*)d_in[2];   // (2048,768)
    const float* bias = (const float*)d_in[3];   // (2048,)

    float* out = (float*)d_out;                  // (8,16,512,512) = 134 MB

    // q/k ws in d_ws (proven size from round 1: 16.8 MB)
    bf16* q_ws = (bf16*)d_ws;                    // [8][16][512][64]
    bf16* k_ws = q_ws + (size_t)8 * 16 * 512 * 64;

    // Converted bf16 inputs live in d_out (fully overwritten by attn_kernel
    // afterwards; kernels are stream-ordered so this is deterministic).
    bf16* Xb = (bf16*)d_out;                     // 6.29 MB
    bf16* Wb = Xb + (size_t)8 * 512 * 768;       // 3.15 MB

    const int NX8 = (8 * 512 * 768) / 8;
    const int NW8 = (2048 * 768) / 8;
    convert_kernel<<<(NX8 + NW8) / 256, 256, 0, stream>>>(X, W, Xb, Wb);
    proj_rope_kernel<<<dim3(32, 16), 256, 0, stream>>>(Xb, Wb, bias, q_ws, k_ws);
    attn_kernel<<<dim3(4, 4, 128), 256, 0, stream>>>(q_ws, k_ws, mask, out);
}